// Round 10
// baseline (181.924 us; speedup 1.0000x reference)
//
#include <hip/hip_runtime.h>

typedef _Float16 f16;
typedef f16 f16x8 __attribute__((ext_vector_type(8)));
typedef float f32x4 __attribute__((ext_vector_type(4)));

constexpr int Bc = 32, Nc = 1024, Dc = 64, Hc = 4, Ec = 16;
constexpr int HPL = 1032;  // attn LDS h_t pitch (f16) = 129 float4 rows

// ---------------------------------------------------------------------------
// Kernel 1: h = input @ W per head -> f16 transposed global [bh][e][1024]
// (coalesced float4 stores via LDS transpose) + fp32 s_src/s_dst.
// DIAGNOSTIC: body repeated `reps` times (identical values each rep;
// asm-opaque input pointer so loads/FMA/stores are re-executed per rep).
// ---------------------------------------------------------------------------
__global__ __launch_bounds__(256) void gat_proj(const float* input,
                                                const float* W,
                                                const float* a,
                                                f16* h16t,
                                                float* s_src,
                                                float* s_dst,
                                                int reps) {
    __shared__ float W_lds[Dc * Ec];
    __shared__ float a_lds[2 * Ec];
    __shared__ alignas(16) f16 T[Ec][264];   // row stride 528B = 33*16B

    const int tid = threadIdx.x;
    const int gid = blockIdx.x * 256 + tid;   // ((b*H + h)*N + n)
    const int n   = gid & (Nc - 1);
    const int bh  = gid >> 10;
    const int hh  = bh & (Hc - 1);
    const int b   = bh >> 2;
    const int n0  = (blockIdx.x & 3) * 256;
    const int nl  = n - n0;

    ((float4*)W_lds)[tid] = ((const float4*)(W + hh * Dc * Ec))[tid];
    if (tid < 2 * Ec) a_lds[tid] = a[tid];
    __syncthreads();

    for (int rep = 0; rep < reps; ++rep) {
        __syncthreads();   // protect T reuse across reps

        const float* ir = input + ((size_t)b * Nc + n) * Dc;
        asm volatile("" : "+v"(ir));   // opaque -> full reload/recompute per rep
        const float4* in_row = (const float4*)ir;

        float acc[Ec];
#pragma unroll
        for (int e = 0; e < Ec; ++e) acc[e] = 0.f;

#pragma unroll
        for (int d4 = 0; d4 < Dc / 4; ++d4) {
            float4 x = in_row[d4];
            float xs[4] = {x.x, x.y, x.z, x.w};
#pragma unroll
            for (int k = 0; k < 4; ++k) {
                const float xv = xs[k];
                const float* wrow = &W_lds[(d4 * 4 + k) * Ec];
#pragma unroll
                for (int e = 0; e < Ec; ++e) acc[e] = fmaf(xv, wrow[e], acc[e]);
            }
        }

        float sd = 0.f, ss = 0.f;
#pragma unroll
        for (int e = 0; e < Ec; ++e) {
            sd = fmaf(acc[e], a_lds[e], sd);        // a_dst = a[:E]
            ss = fmaf(acc[e], a_lds[Ec + e], ss);   // a_src = a[E:]
        }
        s_dst[gid] = sd;
        s_src[gid] = ss;

        // LDS transpose (2B writes, 2-way max alias = free)
#pragma unroll
        for (int e = 0; e < Ec; ++e) T[e][nl] = (f16)acc[e];
        __syncthreads();

        // coalesced store: 512 float4 chunks, 2/thread
        f16* gbase = h16t + (size_t)bh * Ec * Nc;
#pragma unroll
        for (int cc = 0; cc < 2; ++cc) {
            const int c  = cc * 256 + tid;
            const int e2 = c >> 5;
            const int nc = c & 31;
            *(float4*)(gbase + (size_t)e2 * Nc + n0 + nc * 8) =
                *(const float4*)(&T[e2][nc * 8]);
        }
    }
}

// ---------------------------------------------------------------------------
// Kernel 2: EXACT round-6 structure (best measured: 11.45us/rep warm).
// 512 thr, 8 waves, 4 i-tiles/wave, grid (bh, ihalf). P_ij = max(u_j, C_i*v_j);
// out = (P @ h) * rcp(P @ 1) via mfma_f32_16x16x32_f16.
// ---------------------------------------------------------------------------
__global__ __launch_bounds__(512) void gat_attn9(const f16* __restrict__ h16t,
                                                 const float* __restrict__ s_src,
                                                 const float* __restrict__ s_dst,
                                                 float* __restrict__ out) {
    __shared__ alignas(16) f16 h_t[Ec * HPL];    // 33 KB (129 float4 rows)
    __shared__ alignas(16) f16 u_lds[Nc];        // 2 KB
    __shared__ alignas(16) f16 v_lds[Nc];        // 2 KB
    __shared__ float red[8];

    const int bh    = blockIdx.x;      // 0..127
    const int ihalf = blockIdx.y;      // 0..1
    const int tid   = threadIdx.x;
    const int lane  = tid & 63;
    const int wave  = tid >> 6;        // 0..7
    const int row   = lane & 15;       // A-row / D-col index
    const int quad  = lane >> 4;       // K-quadrant

    // ---- stage h_t: global [16][128] float4 -> LDS [16][129] float4 ----
    {
        const float4* src = (const float4*)(h16t + (size_t)bh * Ec * Nc);
        float4* dst = (float4*)h_t;
#pragma unroll
        for (int cc = 0; cc < 4; ++cc) {
            const int c  = cc * 512 + tid;     // 0..2047
            const int e  = c >> 7;
            const int jc = c & 127;
            dst[e * 129 + jc] = src[c];
        }
    }

    // ---- block max of s_dst ----
    const float sd0 = s_dst[bh * Nc + tid];
    const float sd1 = s_dst[bh * Nc + 512 + tid];
    {
        float m = fmaxf(sd0, sd1);
#pragma unroll
        for (int off = 1; off < 64; off <<= 1) m = fmaxf(m, __shfl_xor(m, off, 64));
        if (lane == 0) red[wave] = m;
    }
    __syncthreads();
    float maxd = red[0];
#pragma unroll
    for (int w = 1; w < 8; ++w) maxd = fmaxf(maxd, red[w]);

    // ---- u, v into LDS ----
    u_lds[tid]       = (f16)__expf(sd0 - maxd);
    u_lds[512 + tid] = (f16)__expf(sd1 - maxd);
    v_lds[tid]       = (f16)__expf(0.2f * (sd0 - maxd));
    v_lds[512 + tid] = (f16)__expf(0.2f * (sd1 - maxd));

    // ---- per-row C_i ----
    const int ibase = ihalf * 512 + wave * 64;
    f16x8 C8[4];
#pragma unroll
    for (int it = 0; it < 4; ++it) {
        const float si = s_src[bh * Nc + ibase + it * 16 + row];
        const float c1 = si + maxd;
        const float Cf = (c1 >= 0.f) ? __expf(-0.8f * c1) : 1.0f;
        const f16 ch = (f16)Cf;
        C8[it] = (f16x8){ch, ch, ch, ch, ch, ch, ch, ch};
    }
    __syncthreads();

    f32x4 accN[4] = {};
    f32x4 accD[4] = {};
    const f16 o1 = (f16)1.f;
    const f16x8 ones = {o1, o1, o1, o1, o1, o1, o1, o1};

    const f16* up = u_lds + quad * 8;
    const f16* vp = v_lds + quad * 8;
    const f16* bp = h_t + row * HPL + quad * 8;

#pragma unroll 4
    for (int kt = 0; kt < 32; ++kt) {
        const f16x8 u8 = *(const f16x8*)(up + kt * 32);
        const f16x8 v8 = *(const f16x8*)(vp + kt * 32);
        const f16x8 b8 = *(const f16x8*)(bp + kt * 32);
#pragma unroll
        for (int it = 0; it < 4; ++it) {
            const f16x8 p = __builtin_elementwise_max(u8, C8[it] * v8);
            accN[it] = __builtin_amdgcn_mfma_f32_16x16x32_f16(p, b8,   accN[it], 0, 0, 0);
            accD[it] = __builtin_amdgcn_mfma_f32_16x16x32_f16(p, ones, accD[it], 0, 0, 0);
        }
    }

    // ---- epilogue: D row = quad*4 + r, col = row (m89 C/D layout) ----
#pragma unroll
    for (int it = 0; it < 4; ++it) {
#pragma unroll
        for (int r = 0; r < 4; ++r) {
            const float inv = __builtin_amdgcn_rcpf(accD[it][r]);
            const int i = ibase + it * 16 + quad * 4 + r;
            out[((size_t)(bh * Nc + i)) * Ec + row] = accN[it][r] * inv;
        }
    }
}

extern "C" void kernel_launch(void* const* d_in, const int* in_sizes, int n_in,
                              void* d_out, int out_size, void* d_ws, size_t ws_size,
                              hipStream_t stream) {
    const float* input = (const float*)d_in[0];
    // d_in[1] = adj : UNUSED by the reference
    const float* W = (const float*)d_in[2];
    const float* a = (const float*)d_in[3];
    float* out = (float*)d_out;

    char* ws = (char*)d_ws;
    f16*   h16t  = (f16*)(ws);                       // 128*16*1024*2 = 4,194,304 B
    float* s_src = (float*)(ws + 4194304);           // 524,288 B
    float* s_dst = (float*)(ws + 4194304 + 524288);  // 524,288 B

    // DIAGNOSTIC: 20 proj reps -> proj dispatch rises above the ~40us harness
    // fills and reports direct counters. attn runs single-shot (round-6 cfg).
    gat_proj<<<dim3(Bc * Hc * Nc / 256), dim3(256), 0, stream>>>(input, W, a, h16t,
                                                                 s_src, s_dst, 20);
    gat_attn9<<<dim3(Bc * Hc, 2), dim3(512), 0, stream>>>(h16t, s_src, s_dst, out);
}

// Round 11
// 36.949 us; speedup vs baseline: 4.9237x; 4.9237x over previous
//
#include <hip/hip_runtime.h>

typedef _Float16 f16;
typedef f16 f16x4 __attribute__((ext_vector_type(4)));
typedef f16 f16x8 __attribute__((ext_vector_type(8)));
typedef float f32x4 __attribute__((ext_vector_type(4)));

constexpr int Bc = 32, Nc = 1024, Dc = 64, Hc = 4, Ec = 16;
constexpr int HPL = 1032;  // h_t pitch (f16) = 129 float4 rows (16B-aligned, odd chunks)

// ---------------------------------------------------------------------------
// Single fused kernel. Per block (bh, ihalf):
//  Phase A: h[bh] = input[b] @ W[hh] via mfma_f32_16x16x32_f16 straight into
//           LDS h_t[e][n] (f16); s_dst/s_src in full f32 from input @ (W@a).
//  Phase B: maxd reduce; u = exp(sd-maxd), v = exp(0.2(sd-maxd)) into LDS;
//           C_i = min(1, exp(-0.8(s_i+maxd))).
//  Phase C: EXACT round-6 K-loop: P_ij = max(u_j, C_i*v_j) built packed-f16,
//           out = (P @ h) * rcp(P @ 1) via MFMA.  (measured 11.45us structure)
// ---------------------------------------------------------------------------
__global__ __launch_bounds__(512) void gat_fused(const float* __restrict__ input,
                                                 const float* __restrict__ W,
                                                 const float* __restrict__ a,
                                                 float* __restrict__ out) {
    __shared__ alignas(16) f16 h_t[Ec * HPL];     // 33 KB
    __shared__ alignas(16) float wa_lds[2][Dc];   // 512 B (f32 W@a, both halves)
    __shared__ float ss_lds[Nc];                  // 4 KB (s_src, f32)
    __shared__ alignas(16) f16 u_lds[Nc];         // 2 KB
    __shared__ alignas(16) f16 v_lds[Nc];         // 2 KB
    __shared__ float red[8];

    const int bh    = blockIdx.x;      // 0..127
    const int ihalf = blockIdx.y;      // 0..1
    const int hh    = bh & (Hc - 1);
    const int b     = bh >> 2;
    const int tid   = threadIdx.x;
    const int lane  = tid & 63;
    const int wave  = tid >> 6;        // 0..7
    const int row   = lane & 15;
    const int quad  = lane >> 4;

    // ---- wa[d] = sum_e W[hh][d][e] * a[e] (dst) / a[16+e] (src), f32 ----
    if (tid < Dc) {
        const float* wr = W + hh * Dc * Ec + tid * Ec;
        float wd = 0.f, wsx = 0.f;
#pragma unroll
        for (int e = 0; e < Ec; ++e) {
            wd  = fmaf(wr[e], a[e],      wd);
            wsx = fmaf(wr[e], a[Ec + e], wsx);
        }
        wa_lds[0][tid] = wd;
        wa_lds[1][tid] = wsx;
    }

    // ---- B fragments of W (f16): col = row(e), k = quad*8+j (+32) ----
    f16x8 bW0, bW1;
    {
        const float* wp = W + hh * Dc * Ec + row;
#pragma unroll
        for (int j = 0; j < 8; ++j) {
            bW0[j] = (f16)wp[(quad * 8 + j) * Ec];
            bW1[j] = (f16)wp[(32 + quad * 8 + j) * Ec];
        }
    }

    // ---- Phase A: h via MFMA, 8 M-tiles (16 n each) per wave ----
#pragma unroll
    for (int t = 0; t < 8; ++t) {
        const int n0 = wave * 128 + t * 16;
        const float* ip = input + ((size_t)b * Nc + n0 + row) * Dc;
        f16x8 x0, x1;
#pragma unroll
        for (int j = 0; j < 8; ++j) {
            x0[j] = (f16)ip[quad * 8 + j];
            x1[j] = (f16)ip[32 + quad * 8 + j];
        }
        f32x4 hD = {};
        hD = __builtin_amdgcn_mfma_f32_16x16x32_f16(x0, bW0, hD, 0, 0, 0);
        hD = __builtin_amdgcn_mfma_f32_16x16x32_f16(x1, bW1, hD, 0, 0, 0);
        // D: row(n) = quad*4+r, col(e) = lane&15  ->  h_t[e][n], 4 n packed b64
        f16x4 hp;
#pragma unroll
        for (int r = 0; r < 4; ++r) hp[r] = (f16)hD[r];
        *(f16x4*)(&h_t[row * HPL + n0 + quad * 4]) = hp;
    }
    __syncthreads();   // wa_lds ready for phase-A2; h_t ordered for phase C

    // ---- s in full f32: thread -> n = tid, tid+512 (input L2-hot) ----
    float sdv[2], ssv[2];
#pragma unroll
    for (int nn = 0; nn < 2; ++nn) {
        const int n = nn * 512 + tid;
        const float4* xr  = (const float4*)(input + ((size_t)b * Nc + n) * Dc);
        const float4* wdp = (const float4*)wa_lds[0];
        const float4* wsp = (const float4*)wa_lds[1];
        float sd = 0.f, ss = 0.f;
#pragma unroll
        for (int d4 = 0; d4 < 16; ++d4) {
            float4 x = xr[d4], wd = wdp[d4], wsx = wsp[d4];
            sd = fmaf(x.x, wd.x,  fmaf(x.y, wd.y,  fmaf(x.z, wd.z,  fmaf(x.w, wd.w,  sd))));
            ss = fmaf(x.x, wsx.x, fmaf(x.y, wsx.y, fmaf(x.z, wsx.z, fmaf(x.w, wsx.w, ss))));
        }
        sdv[nn] = sd;
        ssv[nn] = ss;
        ss_lds[n] = ss;
    }

    // ---- block max of s_dst (own regs -> shfl -> red) ----
    {
        float m = fmaxf(sdv[0], sdv[1]);
#pragma unroll
        for (int off = 1; off < 64; off <<= 1) m = fmaxf(m, __shfl_xor(m, off, 64));
        if (lane == 0) red[wave] = m;
    }
    __syncthreads();   // red + ss_lds ready
    float maxd = red[0];
#pragma unroll
    for (int w = 1; w < 8; ++w) maxd = fmaxf(maxd, red[w]);

    // ---- u, v into LDS (from registers) ----
    u_lds[tid]       = (f16)__expf(sdv[0] - maxd);
    u_lds[512 + tid] = (f16)__expf(sdv[1] - maxd);
    v_lds[tid]       = (f16)__expf(0.2f * (sdv[0] - maxd));
    v_lds[512 + tid] = (f16)__expf(0.2f * (sdv[1] - maxd));

    // ---- per-row C_i ----
    const int ibase = ihalf * 512 + wave * 64;
    f16x8 C8[4];
#pragma unroll
    for (int it = 0; it < 4; ++it) {
        const float si = ss_lds[ibase + it * 16 + row];
        const float c1 = si + maxd;
        const float Cf = (c1 >= 0.f) ? __expf(-0.8f * c1) : 1.0f;
        const f16 ch = (f16)Cf;
        C8[it] = (f16x8){ch, ch, ch, ch, ch, ch, ch, ch};
    }
    __syncthreads();   // u/v ready

    // ---- Phase C: EXACT round-6 K-loop ----
    f32x4 accN[4] = {};
    f32x4 accD[4] = {};
    const f16 o1 = (f16)1.f;
    const f16x8 ones = {o1, o1, o1, o1, o1, o1, o1, o1};

    const f16* up = u_lds + quad * 8;
    const f16* vp = v_lds + quad * 8;
    const f16* bp = h_t + row * HPL + quad * 8;

#pragma unroll 4
    for (int kt = 0; kt < 32; ++kt) {
        const f16x8 u8 = *(const f16x8*)(up + kt * 32);
        const f16x8 v8 = *(const f16x8*)(vp + kt * 32);
        const f16x8 b8 = *(const f16x8*)(bp + kt * 32);
#pragma unroll
        for (int it = 0; it < 4; ++it) {
            const f16x8 p = __builtin_elementwise_max(u8, C8[it] * v8);
            accN[it] = __builtin_amdgcn_mfma_f32_16x16x32_f16(p, b8,   accN[it], 0, 0, 0);
            accD[it] = __builtin_amdgcn_mfma_f32_16x16x32_f16(p, ones, accD[it], 0, 0, 0);
        }
    }

    // ---- epilogue: D row = quad*4 + r, col = row ----
#pragma unroll
    for (int it = 0; it < 4; ++it) {
#pragma unroll
        for (int r = 0; r < 4; ++r) {
            const float inv = __builtin_amdgcn_rcpf(accD[it][r]);
            const int i = ibase + it * 16 + quad * 4 + r;
            out[((size_t)(bh * Nc + i)) * Ec + row] = accN[it][r] * inv;
        }
    }
}

extern "C" void kernel_launch(void* const* d_in, const int* in_sizes, int n_in,
                              void* d_out, int out_size, void* d_ws, size_t ws_size,
                              hipStream_t stream) {
    const float* input = (const float*)d_in[0];
    // d_in[1] = adj : UNUSED by the reference
    const float* W = (const float*)d_in[2];
    const float* a = (const float*)d_in[3];
    float* out = (float*)d_out;

    gat_fused<<<dim3(Bc * Hc, 2), dim3(512), 0, stream>>>(input, W, a, out);
}

// Round 12
// 29.604 us; speedup vs baseline: 6.1453x; 1.2481x over previous
//
#include <hip/hip_runtime.h>

typedef _Float16 f16;
typedef f16 f16x4 __attribute__((ext_vector_type(4)));
typedef f16 f16x8 __attribute__((ext_vector_type(8)));
typedef float f32x4 __attribute__((ext_vector_type(4)));

constexpr int Bc = 32, Nc = 1024, Dc = 64, Hc = 4, Ec = 16;
constexpr int HPL = 1032;  // attn LDS h_t pitch (f16) = 129 float4 rows

// ---------------------------------------------------------------------------
// Kernel 1: MFMA projection. Grid 2048 x 256thr (8 blocks/CU).
// Each wave: one 16-row tile of h[bh] = f16(input) @ f16(W[hh]) via two
// mfma_f32_16x16x32_f16, D stored straight to global h16t[bh][e][n] (f16x4).
// s_src/s_dst in f32: per-quad partial dot + shfl_xor reduce (wa in LDS).
// Replaces the scalar proj measured at 9.6us (VALU-latency-bound).
// ---------------------------------------------------------------------------
__global__ __launch_bounds__(256) void gat_projm(const float* __restrict__ input,
                                                 const float* __restrict__ W,
                                                 const float* __restrict__ a,
                                                 f16* __restrict__ h16t,
                                                 float* __restrict__ s_src,
                                                 float* __restrict__ s_dst) {
    __shared__ float wa_lds[2][Dc];   // f32 W@a (0=dst half, 1=src half)

    const int blk   = blockIdx.x;          // 0..2047
    const int bh    = blk >> 4;             // 16 blocks per bh
    const int nbase = (blk & 15) * 64;      // 64 n-rows per block
    const int hh    = bh & (Hc - 1);
    const int b     = bh >> 2;
    const int tid   = threadIdx.x;
    const int lane  = tid & 63;
    const int wave  = tid >> 6;             // 0..3
    const int row   = lane & 15;
    const int quad  = lane >> 4;

    // ---- wa[d] (128 dots of 16, threads 0..127) ----
    if (tid < 2 * Dc) {
        const int d = tid & (Dc - 1), which = tid >> 6;
        const float* wr = W + hh * Dc * Ec + d * Ec;
        const float* av = a + which * Ec;
        float acc = 0.f;
#pragma unroll
        for (int e = 0; e < Ec; ++e) acc = fmaf(wr[e], av[e], acc);
        wa_lds[which][d] = acc;
    }

    // ---- W B-fragments (f16): col = e = row, k = quad*8+j (+32) ----
    f16x8 bW0, bW1;
    {
        const float* wp = W + hh * Dc * Ec + row;
#pragma unroll
        for (int j = 0; j < 8; ++j) {
            bW0[j] = (f16)wp[(quad * 8 + j) * Ec];
            bW1[j] = (f16)wp[(32 + quad * 8 + j) * Ec];
        }
    }

    // ---- MFMA tile: rows n0..n0+15 ----
    const int n0 = nbase + wave * 16;
    {
        const float* ip = input + ((size_t)b * Nc + n0 + row) * Dc;
        f16x8 x0, x1;
#pragma unroll
        for (int j = 0; j < 8; ++j) {
            x0[j] = (f16)ip[quad * 8 + j];
            x1[j] = (f16)ip[32 + quad * 8 + j];
        }
        f32x4 hD = {};
        hD = __builtin_amdgcn_mfma_f32_16x16x32_f16(x0, bW0, hD, 0, 0, 0);
        hD = __builtin_amdgcn_mfma_f32_16x16x32_f16(x1, bW1, hD, 0, 0, 0);
        // D: n = n0 + quad*4 + r, e = row  (m89 layout; validated rounds 4-11)
        f16x4 hp;
#pragma unroll
        for (int r = 0; r < 4; ++r) hp[r] = (f16)hD[r];
        *(f16x4*)(h16t + (size_t)bh * Ec * Nc + row * Nc + n0 + quad * 4) = hp;
    }
    __syncthreads();   // wa_lds ready

    // ---- s (f32): row n0+row, k-quarter = quad; reduce across quads ----
    {
        const int n = n0 + row;
        const float4* xr  = (const float4*)(input + ((size_t)b * Nc + n) * Dc) + quad * 4;
        const float4* wdp = (const float4*)wa_lds[0] + quad * 4;
        const float4* wsp = (const float4*)wa_lds[1] + quad * 4;
        float sd = 0.f, ss = 0.f;
#pragma unroll
        for (int d4 = 0; d4 < 4; ++d4) {
            float4 x = xr[d4], wd = wdp[d4], wsx = wsp[d4];
            sd = fmaf(x.x, wd.x,  fmaf(x.y, wd.y,  fmaf(x.z, wd.z,  fmaf(x.w, wd.w,  sd))));
            ss = fmaf(x.x, wsx.x, fmaf(x.y, wsx.y, fmaf(x.z, wsx.z, fmaf(x.w, wsx.w, ss))));
        }
        sd += __shfl_xor(sd, 16, 64); sd += __shfl_xor(sd, 32, 64);
        ss += __shfl_xor(ss, 16, 64); ss += __shfl_xor(ss, 32, 64);
        if (quad == 0) {
            s_dst[bh * Nc + n] = sd;
            s_src[bh * Nc + n] = ss;
        }
    }
}

// ---------------------------------------------------------------------------
// Kernel 2: EXACT round-6/attn9 structure (measured 11.45us/rep).
// P_ij = max(u_j, C_i*v_j); out = (P @ h) * rcp(P @ 1) via MFMA.
// ---------------------------------------------------------------------------
__global__ __launch_bounds__(512) void gat_attn9(const f16* __restrict__ h16t,
                                                 const float* __restrict__ s_src,
                                                 const float* __restrict__ s_dst,
                                                 float* __restrict__ out) {
    __shared__ alignas(16) f16 h_t[Ec * HPL];    // 33 KB
    __shared__ alignas(16) f16 u_lds[Nc];        // 2 KB
    __shared__ alignas(16) f16 v_lds[Nc];        // 2 KB
    __shared__ float red[8];

    const int bh    = blockIdx.x;      // 0..127
    const int ihalf = blockIdx.y;      // 0..1
    const int tid   = threadIdx.x;
    const int lane  = tid & 63;
    const int wave  = tid >> 6;        // 0..7
    const int row   = lane & 15;
    const int quad  = lane >> 4;

    // ---- stage h_t: global [16][128] float4 -> LDS [16][129] float4 ----
    {
        const float4* src = (const float4*)(h16t + (size_t)bh * Ec * Nc);
        float4* dst = (float4*)h_t;
#pragma unroll
        for (int cc = 0; cc < 4; ++cc) {
            const int c  = cc * 512 + tid;     // 0..2047
            const int e  = c >> 7;
            const int jc = c & 127;
            dst[e * 129 + jc] = src[c];
        }
    }

    // ---- block max of s_dst ----
    const float sd0 = s_dst[bh * Nc + tid];
    const float sd1 = s_dst[bh * Nc + 512 + tid];
    {
        float m = fmaxf(sd0, sd1);
#pragma unroll
        for (int off = 1; off < 64; off <<= 1) m = fmaxf(m, __shfl_xor(m, off, 64));
        if (lane == 0) red[wave] = m;
    }
    __syncthreads();
    float maxd = red[0];
#pragma unroll
    for (int w = 1; w < 8; ++w) maxd = fmaxf(maxd, red[w]);

    // ---- u, v into LDS ----
    u_lds[tid]       = (f16)__expf(sd0 - maxd);
    u_lds[512 + tid] = (f16)__expf(sd1 - maxd);
    v_lds[tid]       = (f16)__expf(0.2f * (sd0 - maxd));
    v_lds[512 + tid] = (f16)__expf(0.2f * (sd1 - maxd));

    // ---- per-row C_i ----
    const int ibase = ihalf * 512 + wave * 64;
    f16x8 C8[4];
#pragma unroll
    for (int it = 0; it < 4; ++it) {
        const float si = s_src[bh * Nc + ibase + it * 16 + row];
        const float c1 = si + maxd;
        const float Cf = (c1 >= 0.f) ? __expf(-0.8f * c1) : 1.0f;
        const f16 ch = (f16)Cf;
        C8[it] = (f16x8){ch, ch, ch, ch, ch, ch, ch, ch};
    }
    __syncthreads();

    f32x4 accN[4] = {};
    f32x4 accD[4] = {};
    const f16 o1 = (f16)1.f;
    const f16x8 ones = {o1, o1, o1, o1, o1, o1, o1, o1};

    const f16* up = u_lds + quad * 8;
    const f16* vp = v_lds + quad * 8;
    const f16* bp = h_t + row * HPL + quad * 8;

#pragma unroll 4
    for (int kt = 0; kt < 32; ++kt) {
        const f16x8 u8 = *(const f16x8*)(up + kt * 32);
        const f16x8 v8 = *(const f16x8*)(vp + kt * 32);
        const f16x8 b8 = *(const f16x8*)(bp + kt * 32);
#pragma unroll
        for (int it = 0; it < 4; ++it) {
            const f16x8 p = __builtin_elementwise_max(u8, C8[it] * v8);
            accN[it] = __builtin_amdgcn_mfma_f32_16x16x32_f16(p, b8,   accN[it], 0, 0, 0);
            accD[it] = __builtin_amdgcn_mfma_f32_16x16x32_f16(p, ones, accD[it], 0, 0, 0);
        }
    }

    // ---- epilogue: D row = quad*4 + r, col = row ----
#pragma unroll
    for (int it = 0; it < 4; ++it) {
#pragma unroll
        for (int r = 0; r < 4; ++r) {
            const float inv = __builtin_amdgcn_rcpf(accD[it][r]);
            const int i = ibase + it * 16 + quad * 4 + r;
            out[((size_t)(bh * Nc + i)) * Ec + row] = accN[it][r] * inv;
        }
    }
}

extern "C" void kernel_launch(void* const* d_in, const int* in_sizes, int n_in,
                              void* d_out, int out_size, void* d_ws, size_t ws_size,
                              hipStream_t stream) {
    const float* input = (const float*)d_in[0];
    // d_in[1] = adj : UNUSED by the reference
    const float* W = (const float*)d_in[2];
    const float* a = (const float*)d_in[3];
    float* out = (float*)d_out;

    char* ws = (char*)d_ws;
    f16*   h16t  = (f16*)(ws);                       // 4,194,304 B
    float* s_src = (float*)(ws + 4194304);           // 524,288 B
    float* s_dst = (float*)(ws + 4194304 + 524288);  // 524,288 B

    gat_projm<<<dim3(2048), dim3(256), 0, stream>>>(input, W, a, h16t, s_src, s_dst);
    gat_attn9<<<dim3(Bc * Hc, 2), dim3(512), 0, stream>>>(h16t, s_src, s_dst, out);
}

// Round 13
// 25.589 us; speedup vs baseline: 7.1095x; 1.1569x over previous
//
#include <hip/hip_runtime.h>

typedef _Float16 f16;
typedef f16 f16x8 __attribute__((ext_vector_type(8)));
typedef float f32x4 __attribute__((ext_vector_type(4)));

constexpr int Bc = 32, Nc = 1024, Dc = 64, Hc = 4, Ec = 16;
constexpr int HPL = 1032;  // attn LDS h_t pitch (f16) = 129 float4 rows

// ---------------------------------------------------------------------------
// Kernel 1: scalar proj, parallelism doubled vs the 9.6us version (round-10
// counters: latency-bound, 22% occupancy, 2 blocks/CU). Now: one thread per
// (n, e-half) -> 1024 blocks x 256 thr = 4 blocks/CU, 512-FMA chains with 8
// independent accs. s via shfl_xor(1) pair-combine. h16t stored transposed
// f16 [bh][e][n] through LDS transpose + coalesced float4 stores.
// ---------------------------------------------------------------------------
__global__ __launch_bounds__(256) void gat_proj2(const float* __restrict__ input,
                                                 const float* __restrict__ W,
                                                 const float* __restrict__ a,
                                                 f16* __restrict__ h16t,
                                                 float* __restrict__ s_src,
                                                 float* __restrict__ s_dst) {
    __shared__ float W_lds[Dc * Ec];          // 4 KB
    __shared__ float a_lds[2 * Ec];
    __shared__ alignas(16) f16 T[Ec][136];    // 128 + 8 pad (row stride 272B = 17*16B)

    const int tid  = threadIdx.x;
    const int blk  = blockIdx.x;           // 0..1023
    const int bh   = blk >> 3;             // 8 blocks per bh
    const int hh   = bh & (Hc - 1);
    const int b    = bh >> 2;
    const int n0   = (blk & 7) * 128;
    const int half = tid & 1;              // e-half (0: e0..7, 1: e8..15)
    const int nl   = tid >> 1;             // 0..127
    const int n    = n0 + nl;

    ((float4*)W_lds)[tid] = ((const float4*)(W + hh * Dc * Ec))[tid];
    if (tid < 2 * Ec) a_lds[tid] = a[tid];
    __syncthreads();

    const float4* in_row = (const float4*)(input + ((size_t)b * Nc + n) * Dc);

    float acc[8];
#pragma unroll
    for (int e = 0; e < 8; ++e) acc[e] = 0.f;

#pragma unroll
    for (int d4 = 0; d4 < Dc / 4; ++d4) {
        float4 x = in_row[d4];
        float xs[4] = {x.x, x.y, x.z, x.w};
#pragma unroll
        for (int k = 0; k < 4; ++k) {
            const float xv = xs[k];
            const float* wrow = &W_lds[(d4 * 4 + k) * Ec + half * 8];
#pragma unroll
            for (int e = 0; e < 8; ++e) acc[e] = fmaf(xv, wrow[e], acc[e]);
        }
    }

    // s: half-partials combined across the (even,odd) lane pair (same n)
    {
        float sd = 0.f, ss = 0.f;
#pragma unroll
        for (int e = 0; e < 8; ++e) {
            sd = fmaf(acc[e], a_lds[half * 8 + e],      sd);   // a_dst = a[:16]
            ss = fmaf(acc[e], a_lds[16 + half * 8 + e], ss);   // a_src = a[16:]
        }
        sd += __shfl_xor(sd, 1, 64);
        ss += __shfl_xor(ss, 1, 64);
        if (half == 0) {
            s_dst[bh * Nc + n] = sd;
            s_src[bh * Nc + n] = ss;
        }
    }

    // LDS transpose then coalesced f16 stores (16 e-rows x 128 n = 256 float4)
#pragma unroll
    for (int e = 0; e < 8; ++e) T[half * 8 + e][nl] = (f16)acc[e];
    __syncthreads();

    {
        const int e2 = tid >> 4;          // 0..15
        const int ch = tid & 15;          // 0..15 float4 chunks of 8 f16
        *(float4*)(h16t + (size_t)bh * Ec * Nc + (size_t)e2 * Nc + n0 + ch * 8) =
            *(const float4*)(&T[e2][ch * 8]);
    }
}

// ---------------------------------------------------------------------------
// Kernel 2: EXACT round-6/round-12 structure (measured 11.45us/rep warm).
// P_ij = max(u_j, C_i*v_j); out = (P @ h) * rcp(P @ 1) via mfma_f32_16x16x32_f16.
// ---------------------------------------------------------------------------
__global__ __launch_bounds__(512) void gat_attn9(const f16* __restrict__ h16t,
                                                 const float* __restrict__ s_src,
                                                 const float* __restrict__ s_dst,
                                                 float* __restrict__ out) {
    __shared__ alignas(16) f16 h_t[Ec * HPL];    // 33 KB
    __shared__ alignas(16) f16 u_lds[Nc];        // 2 KB
    __shared__ alignas(16) f16 v_lds[Nc];        // 2 KB
    __shared__ float red[8];

    const int bh    = blockIdx.x;      // 0..127
    const int ihalf = blockIdx.y;      // 0..1
    const int tid   = threadIdx.x;
    const int lane  = tid & 63;
    const int wave  = tid >> 6;        // 0..7
    const int row   = lane & 15;
    const int quad  = lane >> 4;

    // ---- stage h_t: global [16][128] float4 -> LDS [16][129] float4 ----
    {
        const float4* src = (const float4*)(h16t + (size_t)bh * Ec * Nc);
        float4* dst = (float4*)h_t;
#pragma unroll
        for (int cc = 0; cc < 4; ++cc) {
            const int c  = cc * 512 + tid;     // 0..2047
            const int e  = c >> 7;
            const int jc = c & 127;
            dst[e * 129 + jc] = src[c];
        }
    }

    // ---- block max of s_dst ----
    const float sd0 = s_dst[bh * Nc + tid];
    const float sd1 = s_dst[bh * Nc + 512 + tid];
    {
        float m = fmaxf(sd0, sd1);
#pragma unroll
        for (int off = 1; off < 64; off <<= 1) m = fmaxf(m, __shfl_xor(m, off, 64));
        if (lane == 0) red[wave] = m;
    }
    __syncthreads();
    float maxd = red[0];
#pragma unroll
    for (int w = 1; w < 8; ++w) maxd = fmaxf(maxd, red[w]);

    // ---- u, v into LDS ----
    u_lds[tid]       = (f16)__expf(sd0 - maxd);
    u_lds[512 + tid] = (f16)__expf(sd1 - maxd);
    v_lds[tid]       = (f16)__expf(0.2f * (sd0 - maxd));
    v_lds[512 + tid] = (f16)__expf(0.2f * (sd1 - maxd));

    // ---- per-row C_i ----
    const int ibase = ihalf * 512 + wave * 64;
    f16x8 C8[4];
#pragma unroll
    for (int it = 0; it < 4; ++it) {
        const float si = s_src[bh * Nc + ibase + it * 16 + row];
        const float c1 = si + maxd;
        const float Cf = (c1 >= 0.f) ? __expf(-0.8f * c1) : 1.0f;
        const f16 ch = (f16)Cf;
        C8[it] = (f16x8){ch, ch, ch, ch, ch, ch, ch, ch};
    }
    __syncthreads();

    f32x4 accN[4] = {};
    f32x4 accD[4] = {};
    const f16 o1 = (f16)1.f;
    const f16x8 ones = {o1, o1, o1, o1, o1, o1, o1, o1};

    const f16* up = u_lds + quad * 8;
    const f16* vp = v_lds + quad * 8;
    const f16* bp = h_t + row * HPL + quad * 8;

#pragma unroll 4
    for (int kt = 0; kt < 32; ++kt) {
        const f16x8 u8 = *(const f16x8*)(up + kt * 32);
        const f16x8 v8 = *(const f16x8*)(vp + kt * 32);
        const f16x8 b8 = *(const f16x8*)(bp + kt * 32);
#pragma unroll
        for (int it = 0; it < 4; ++it) {
            const f16x8 p = __builtin_elementwise_max(u8, C8[it] * v8);
            accN[it] = __builtin_amdgcn_mfma_f32_16x16x32_f16(p, b8,   accN[it], 0, 0, 0);
            accD[it] = __builtin_amdgcn_mfma_f32_16x16x32_f16(p, ones, accD[it], 0, 0, 0);
        }
    }

    // ---- epilogue: D row = quad*4 + r, col = row ----
#pragma unroll
    for (int it = 0; it < 4; ++it) {
#pragma unroll
        for (int r = 0; r < 4; ++r) {
            const float inv = __builtin_amdgcn_rcpf(accD[it][r]);
            const int i = ibase + it * 16 + quad * 4 + r;
            out[((size_t)(bh * Nc + i)) * Ec + row] = accN[it][r] * inv;
        }
    }
}

extern "C" void kernel_launch(void* const* d_in, const int* in_sizes, int n_in,
                              void* d_out, int out_size, void* d_ws, size_t ws_size,
                              hipStream_t stream) {
    const float* input = (const float*)d_in[0];
    // d_in[1] = adj : UNUSED by the reference
    const float* W = (const float*)d_in[2];
    const float* a = (const float*)d_in[3];
    float* out = (float*)d_out;

    char* ws = (char*)d_ws;
    f16*   h16t  = (f16*)(ws);                       // 4,194,304 B
    float* s_src = (float*)(ws + 4194304);           // 524,288 B
    float* s_dst = (float*)(ws + 4194304 + 524288);  // 524,288 B

    gat_proj2<<<dim3(1024), dim3(256), 0, stream>>>(input, W, a, h16t, s_src, s_dst);
    gat_attn9<<<dim3(Bc * Hc, 2), dim3(512), 0, stream>>>(h16t, s_src, s_dst, out);
}

// Round 14
// 23.841 us; speedup vs baseline: 7.6308x; 1.0733x over previous
//
#include <hip/hip_runtime.h>

typedef _Float16 f16;
typedef f16 f16x8 __attribute__((ext_vector_type(8)));
typedef float f32x4 __attribute__((ext_vector_type(4)));

constexpr int Bc = 32, Nc = 1024, Dc = 64, Hc = 4, Ec = 16;
constexpr int HPL = 1032;  // attn LDS hv pitch (f16) = 129 float4 rows

// ---------------------------------------------------------------------------
// Kernel 1: UNCHANGED round-13 proj2 (measured-good: 4 blocks/CU).
// ---------------------------------------------------------------------------
__global__ __launch_bounds__(256) void gat_proj2(const float* __restrict__ input,
                                                 const float* __restrict__ W,
                                                 const float* __restrict__ a,
                                                 f16* __restrict__ h16t,
                                                 float* __restrict__ s_src,
                                                 float* __restrict__ s_dst) {
    __shared__ float W_lds[Dc * Ec];          // 4 KB
    __shared__ float a_lds[2 * Ec];
    __shared__ alignas(16) f16 T[Ec][136];    // 128 + 8 pad

    const int tid  = threadIdx.x;
    const int blk  = blockIdx.x;           // 0..1023
    const int bh   = blk >> 3;
    const int hh   = bh & (Hc - 1);
    const int b    = bh >> 2;
    const int n0   = (blk & 7) * 128;
    const int half = tid & 1;
    const int nl   = tid >> 1;
    const int n    = n0 + nl;

    ((float4*)W_lds)[tid] = ((const float4*)(W + hh * Dc * Ec))[tid];
    if (tid < 2 * Ec) a_lds[tid] = a[tid];
    __syncthreads();

    const float4* in_row = (const float4*)(input + ((size_t)b * Nc + n) * Dc);

    float acc[8];
#pragma unroll
    for (int e = 0; e < 8; ++e) acc[e] = 0.f;

#pragma unroll
    for (int d4 = 0; d4 < Dc / 4; ++d4) {
        float4 x = in_row[d4];
        float xs[4] = {x.x, x.y, x.z, x.w};
#pragma unroll
        for (int k = 0; k < 4; ++k) {
            const float xv = xs[k];
            const float* wrow = &W_lds[(d4 * 4 + k) * Ec + half * 8];
#pragma unroll
            for (int e = 0; e < 8; ++e) acc[e] = fmaf(xv, wrow[e], acc[e]);
        }
    }

    {
        float sd = 0.f, ss = 0.f;
#pragma unroll
        for (int e = 0; e < 8; ++e) {
            sd = fmaf(acc[e], a_lds[half * 8 + e],      sd);
            ss = fmaf(acc[e], a_lds[16 + half * 8 + e], ss);
        }
        sd += __shfl_xor(sd, 1, 64);
        ss += __shfl_xor(ss, 1, 64);
        if (half == 0) {
            s_dst[bh * Nc + n] = sd;
            s_src[bh * Nc + n] = ss;
        }
    }

#pragma unroll
    for (int e = 0; e < 8; ++e) T[half * 8 + e][nl] = (f16)acc[e];
    __syncthreads();

    {
        const int e2 = tid >> 4;
        const int ch = tid & 15;
        *(float4*)(h16t + (size_t)bh * Ec * Nc + (size_t)e2 * Nc + n0 + ch * 8) =
            *(const float4*)(&T[e2][ch * 8]);
    }
}

// ---------------------------------------------------------------------------
// Kernel 2: VALU-halved K-loop.  P_ij = v_j * max(w_j, C_i)  (exact refactor
// of max(u_j, C_i*v_j); w = e^{0.8(sd-maxd)}, v = e^{0.2(sd-maxd)}, both <=1).
// B-operands carry v: hv[e][j] = v_j*h[e][j]; den-B = v8 (column-constant).
// Inner loop per (it,kt): ONE pk_max quad (4 instrs) + 2 MFMA.  (was 8 + 2)
// ---------------------------------------------------------------------------
__global__ __launch_bounds__(512) void gat_attn10(const f16* __restrict__ h16t,
                                                  const float* __restrict__ s_src,
                                                  const float* __restrict__ s_dst,
                                                  float* __restrict__ out) {
    __shared__ alignas(16) f16 hv_t[Ec * HPL];   // 33 KB (v-scaled h)
    __shared__ alignas(16) f16 w_lds[Nc];        // 2 KB
    __shared__ alignas(16) f16 v_lds[Nc];        // 2 KB
    __shared__ float red[8];

    const int bh    = blockIdx.x;      // 0..127
    const int ihalf = blockIdx.y;      // 0..1
    const int tid   = threadIdx.x;
    const int lane  = tid & 63;
    const int wave  = tid >> 6;        // 0..7
    const int row   = lane & 15;
    const int quad  = lane >> 4;

    // ---- issue h chunk loads early (latency hides under reduce/exp) ----
    f16x8 h8[4];
    {
        const float4* src = (const float4*)(h16t + (size_t)bh * Ec * Nc);
#pragma unroll
        for (int cc = 0; cc < 4; ++cc) {
            float4 t = src[cc * 512 + tid];
            h8[cc] = *(f16x8*)&t;
        }
    }

    // ---- block max of s_dst ----
    const float sd0 = s_dst[bh * Nc + tid];
    const float sd1 = s_dst[bh * Nc + 512 + tid];
    {
        float m = fmaxf(sd0, sd1);
#pragma unroll
        for (int off = 1; off < 64; off <<= 1) m = fmaxf(m, __shfl_xor(m, off, 64));
        if (lane == 0) red[wave] = m;
    }
    __syncthreads();
    float maxd = red[0];
#pragma unroll
    for (int w = 1; w < 8; ++w) maxd = fmaxf(maxd, red[w]);

    // ---- w, v into LDS ----
    w_lds[tid]       = (f16)__expf(0.8f * (sd0 - maxd));
    w_lds[512 + tid] = (f16)__expf(0.8f * (sd1 - maxd));
    v_lds[tid]       = (f16)__expf(0.2f * (sd0 - maxd));
    v_lds[512 + tid] = (f16)__expf(0.2f * (sd1 - maxd));

    // ---- per-row C_i ----
    const int ibase = ihalf * 512 + wave * 64;
    f16x8 C8[4];
#pragma unroll
    for (int it = 0; it < 4; ++it) {
        const float si = s_src[bh * Nc + ibase + it * 16 + row];
        const float c1 = si + maxd;
        const float Cf = (c1 >= 0.f) ? __expf(-0.8f * c1) : 1.0f;
        const f16 ch = (f16)Cf;
        C8[it] = (f16x8){ch, ch, ch, ch, ch, ch, ch, ch};
    }
    __syncthreads();   // v_lds ready for hv build

    // ---- build hv = v * h into LDS ----
    {
        float4* dst = (float4*)hv_t;
#pragma unroll
        for (int cc = 0; cc < 4; ++cc) {
            const int c  = cc * 512 + tid;     // 0..2047
            const int e  = c >> 7;
            const int jc = c & 127;
            const f16x8 v8 = *(const f16x8*)(&v_lds[jc * 8]);
            f16x8 hv = h8[cc] * v8;            // 4 pk muls
            dst[e * 129 + jc] = *(float4*)&hv;
        }
    }
    __syncthreads();

    f32x4 accN[4] = {};
    f32x4 accD[4] = {};

    const f16* wp = w_lds + quad * 8;
    const f16* vp = v_lds + quad * 8;
    const f16* bp = hv_t + row * HPL + quad * 8;

#pragma unroll 4
    for (int kt = 0; kt < 32; ++kt) {
        const f16x8 w8  = *(const f16x8*)(wp + kt * 32);
        const f16x8 v8  = *(const f16x8*)(vp + kt * 32);
        const f16x8 hv8 = *(const f16x8*)(bp + kt * 32);
#pragma unroll
        for (int it = 0; it < 4; ++it) {
            const f16x8 pm = __builtin_elementwise_max(w8, C8[it]);   // 4 pk instrs
            accN[it] = __builtin_amdgcn_mfma_f32_16x16x32_f16(pm, hv8, accN[it], 0, 0, 0);
            accD[it] = __builtin_amdgcn_mfma_f32_16x16x32_f16(pm, v8,  accD[it], 0, 0, 0);
        }
    }

    // ---- epilogue: D row = quad*4 + r, col = row ----
#pragma unroll
    for (int it = 0; it < 4; ++it) {
#pragma unroll
        for (int r = 0; r < 4; ++r) {
            const float inv = __builtin_amdgcn_rcpf(accD[it][r]);
            const int i = ibase + it * 16 + quad * 4 + r;
            out[((size_t)(bh * Nc + i)) * Ec + row] = accN[it][r] * inv;
        }
    }
}

extern "C" void kernel_launch(void* const* d_in, const int* in_sizes, int n_in,
                              void* d_out, int out_size, void* d_ws, size_t ws_size,
                              hipStream_t stream) {
    const float* input = (const float*)d_in[0];
    // d_in[1] = adj : UNUSED by the reference
    const float* W = (const float*)d_in[2];
    const float* a = (const float*)d_in[3];
    float* out = (float*)d_out;

    char* ws = (char*)d_ws;
    f16*   h16t  = (f16*)(ws);                       // 4,194,304 B
    float* s_src = (float*)(ws + 4194304);           // 524,288 B
    float* s_dst = (float*)(ws + 4194304 + 524288);  // 524,288 B

    gat_proj2<<<dim3(1024), dim3(256), 0, stream>>>(input, W, a, h16t, s_src, s_dst);
    gat_attn10<<<dim3(Bc * Hc, 2), dim3(512), 0, stream>>>(h16t, s_src, s_dst, out);
}